// Round 1
// 1016.423 us; speedup vs baseline: 1.1157x; 1.1157x over previous
//
#include <hip/hip_runtime.h>
#include <math.h>

#define PAD_ID 50257
#define B_ 8
#define S_ 2048
#define D_ 2048
#define H_ 16
#define HD_ 128
#define L_ 2
#define DC_ 4096
#define I_ 16384
#define EPS_ 1e-5f

__device__ __forceinline__ int rfl(int x){ return __builtin_amdgcn_readfirstlane(x); }

// ---------------- kA: last non-pad index per sequence ----------------
__global__ __launch_bounds__(256) void kA(const int* __restrict__ ids, int* __restrict__ idx){
  int b = blockIdx.x, t = threadIdx.x;
  __shared__ int red[256];
  int best = -1;
  for (int s = t; s < S_; s += 256)
    if (ids[b*S_+s] != PAD_ID) best = s;   // monotone loop -> best = max nonpad s in this thread's strided set
  red[t] = best; __syncthreads();
  for (int off=128; off; off>>=1){ if (t<off) red[t] = max(red[t], red[t+off]); __syncthreads(); }
  if (t==0) idx[b] = max(red[0], 0);
}

// ---------------- kA2: LN of last-token row -> lnlT[l][d][b] ----------------
__global__ __launch_bounds__(256) void kA2(const float* __restrict__ hs0, const float* __restrict__ hs1,
                    const int* __restrict__ idx,
                    const float* __restrict__ g, const float* __restrict__ bt,
                    float* __restrict__ lnlT){
  int b = blockIdx.x, l = blockIdx.y, t = threadIdx.x;
  const float* hs = (l==0?hs0:hs1);
  const float* row = hs + ((size_t)b*S_ + idx[b])*D_;
  int d0 = t*8;
  float x[8]; float s=0.f, ss=0.f;
  #pragma unroll
  for(int k=0;k<8;k++){ x[k]=row[d0+k]; s+=x[k]; ss+=x[k]*x[k]; }
  __shared__ float r1[256], r2[256];
  r1[t]=s; r2[t]=ss; __syncthreads();
  for(int off=128; off; off>>=1){ if(t<off){ r1[t]+=r1[t+off]; r2[t]+=r2[t+off]; } __syncthreads(); }
  float m = r1[0]*(1.0f/D_); float var = r2[0]*(1.0f/D_) - m*m;
  float rstd = rsqrtf(var + EPS_);
  #pragma unroll
  for(int k=0;k<8;k++){
    int d = d0+k;
    lnlT[((size_t)l*D_ + d)*8 + b] = (x[k]-m)*rstd*g[l*D_+d] + bt[l*D_+d];
  }
}

// ---------------- gemv8: outT[i][b] += sum_c Xt[c][b] * W[c][i] (8 rows) ----------------
__global__ __launch_bounds__(256) void gemv8(
    const float* __restrict__ W, const float* __restrict__ Xt, float* __restrict__ outAcc,
    int C, int N, int cs, long wStride, long xStride, long oStride){
  int t = threadIdx.x;
  int l = blockIdx.z;
  W += (size_t)l*wStride; Xt += (size_t)l*xStride; outAcc += (size_t)l*oStride;
  int lane = t & 63;
  int w = rfl(t >> 6);
  int cpw = C/(cs*4);
  int c0 = (blockIdx.y*4 + w)*cpw;
  float acc[8] = {0,0,0,0,0,0,0,0};
  const float* xp = Xt + (size_t)c0*8;
  const float* wp = W + (size_t)c0*N + (size_t)blockIdx.x*64 + lane;
  #pragma unroll 4
  for (int c=0; c<cpw; c++){
    float wv = wp[(size_t)c*N];
    #pragma unroll
    for(int r=0;r<8;r++) acc[r] += xp[c*8+r]*wv;
  }
  __shared__ float red[4][64][8];
  #pragma unroll
  for(int r=0;r<8;r++) red[w][lane][r] = acc[r];
  __syncthreads();
  if (t < 64){
    #pragma unroll
    for(int r=0;r<8;r++){
      float s = red[0][t][r]+red[1][t][r]+red[2][t][r]+red[3][t][r];
      atomicAdd(&outAcc[((size_t)blockIdx.x*64 + t)*8 + r], s);
    }
  }
}

// ---------------- kC: qk -> gqk[l][b][h][d'], Sg, Sb ----------------
__global__ __launch_bounds__(256) void kC(
    const float* __restrict__ Wk, const float* __restrict__ qT,
    const float* __restrict__ g, const float* __restrict__ bt,
    float* __restrict__ gqk, float* __restrict__ Sg, float* __restrict__ Sb){
  int t = threadIdx.x;
  int h = blockIdx.y; int l = blockIdx.z;
  int dp = blockIdx.x*256 + t;
  const float* wr = Wk + (size_t)l*D_*D_ + (size_t)dp*D_ + h*HD_;
  const float* qB = qT + ((size_t)l*D_ + h*HD_)*8;
  float a[8]={0,0,0,0,0,0,0,0};
  #pragma unroll 4
  for (int j4=0;j4<32;j4++){
    float4 wv = *(const float4*)(wr + j4*4);
    const float* qp = qB + j4*32;
    #pragma unroll
    for(int r=0;r<8;r++)
      a[r] += wv.x*qp[r] + wv.y*qp[8+r] + wv.z*qp[16+r] + wv.w*qp[24+r];
  }
  float gg = g[l*D_+dp], bb = bt[l*D_+dp];
  float sgl[8], sbl[8];
  #pragma unroll
  for(int r=0;r<8;r++){
    float gq = gg*a[r];
    gqk[((size_t)(l*8+r)*H_ + h)*D_ + dp] = gq;
    sgl[r] = gq;
    sbl[r] = bb*a[r];
  }
  __shared__ float red[256][8];
  #pragma unroll
  for(int r=0;r<8;r++) red[t][r]=sgl[r];
  __syncthreads();
  for(int off=128; off; off>>=1){ if(t<off){ for(int r=0;r<8;r++) red[t][r]+=red[t+off][r]; } __syncthreads(); }
  if (t<8) atomicAdd(&Sg[(l*8+t)*H_ + h], red[0][t]);
  __syncthreads();
  #pragma unroll
  for(int r=0;r<8;r++) red[t][r]=sbl[r];
  __syncthreads();
  for(int off=128; off; off>>=1){ if(t<off){ for(int r=0;r<8;r++) red[t][r]+=red[t+off][r]; } __syncthreads(); }
  if (t<8) atomicAdd(&Sb[(l*8+t)*H_ + h], red[0][t]);
}

// ---------------- kD: scores partials (K-split x2, R=4 row blocking, LDS-staged gq) ----------------
// accP[kh][lb][h][s], sumP[kh][lb][s], sqP[kh][lb][s]
__global__ __launch_bounds__(256) void kD(
    const float* __restrict__ hs0, const float* __restrict__ hs1,
    const float* __restrict__ gqk,
    float* __restrict__ accP, float* __restrict__ sumP, float* __restrict__ sqP){
  int t = threadIdx.x;
  int sc = blockIdx.x & 31, kh = blockIdx.x >> 5;
  int b = blockIdx.y, l = blockIdx.z;
  int lb = l*8 + b;
  const float* hs = (l==0?hs0:hs1) + (size_t)b*S_*D_;
  const float* gqp = gqk + (size_t)lb*H_*D_;
  int s0 = sc*64;
  int kb = kh*1024;
  __shared__ float smem[64*66 + 16*68];   // x tile [64][66] + gq tile [16][68]; reused as redL[64][73]
  float* xT = smem;
  float* gT = smem + 64*66;
  int rq = t & 15, jg = t >> 4;     // row quad (4 rows), col group (4 cols)
  int r0 = rq*4, jc = jg*4;
  float acc[4][16];
  #pragma unroll
  for(int rr=0;rr<4;rr++){
    #pragma unroll
    for(int h=0;h<16;h++) acc[rr][h]=0.f;
  }
  float sum[4]={0.f,0.f,0.f,0.f}, sq[4]={0.f,0.f,0.f,0.f};
  for (int c=0;c<16;c++){
    int cb = kb + c*64;
    // stage X tile [64 rows][64 cols]
    #pragma unroll
    for (int q=0;q<4;q++){
      int fid = t + q*256;
      int row = fid >> 4, jo = (fid & 15)*4;
      float4 v = *(const float4*)(hs + (size_t)(s0+row)*D_ + cb + jo);
      float2* wp = (float2*)&xT[row*66 + jo];
      wp[0] = make_float2(v.x, v.y);
      wp[1] = make_float2(v.z, v.w);
    }
    // stage gq tile [16 h][64 cols]
    {
      int hh = t >> 4, jo = (t & 15)*4;
      float4 gv = *(const float4*)(gqp + (size_t)hh*D_ + cb + jo);
      *(float4*)&gT[hh*68 + jo] = gv;
    }
    __syncthreads();
    float xv[4][4];
    #pragma unroll
    for (int rr=0;rr<4;rr++){
      const float2* xp = (const float2*)&xT[(r0+rr)*66 + jc];
      float2 xa = xp[0], xb = xp[1];
      xv[rr][0]=xa.x; xv[rr][1]=xa.y; xv[rr][2]=xb.x; xv[rr][3]=xb.y;
      sum[rr] += xa.x + xa.y + xb.x + xb.y;
      sq[rr]  += xa.x*xa.x + xa.y*xa.y + xb.x*xb.x + xb.y*xb.y;
    }
    #pragma unroll
    for (int h=0;h<16;h++){
      float4 gv = *(const float4*)&gT[h*68 + jc];
      #pragma unroll
      for (int rr=0;rr<4;rr++)
        acc[rr][h] += xv[rr][0]*gv.x + xv[rr][1]*gv.y + xv[rr][2]*gv.z + xv[rr][3]*gv.w;
    }
    __syncthreads();
  }
  // reduce over the 4 col-groups inside each wave (lane bits 4,5)
  #pragma unroll
  for (int rr=0;rr<4;rr++){
    #pragma unroll
    for (int h=0;h<16;h++){
      float v = acc[rr][h];
      v += __shfl_xor(v, 16);
      v += __shfl_xor(v, 32);
      acc[rr][h] = v;
    }
    float sv = sum[rr]; sv += __shfl_xor(sv, 16); sv += __shfl_xor(sv, 32); sum[rr] = sv;
    float qv = sq[rr];  qv += __shfl_xor(qv, 16); qv += __shfl_xor(qv, 32); sq[rr]  = qv;
  }
  __syncthreads();   // done with xT/gT, reuse as redL
  float* redL = smem;  // [64 entries][73]
  int w = t >> 6;
  if ((t & 63) < 16){
    float* p = &redL[(w*16 + rq)*73];
    #pragma unroll
    for (int rr=0;rr<4;rr++){
      #pragma unroll
      for (int h=0;h<16;h++) p[rr*16+h] = acc[rr][h];
      p[64+rr] = sum[rr];
      p[68+rr] = sq[rr];
    }
  }
  __syncthreads();
  if (t < 64){
    int frq = t >> 2, frr = t & 3;
    float ah[16];
    #pragma unroll
    for(int h=0;h<16;h++) ah[h]=0.f;
    float s1=0.f, s2=0.f;
    #pragma unroll
    for (int ww=0; ww<4; ww++){
      const float* p = &redL[(ww*16 + frq)*73];
      #pragma unroll
      for(int h=0;h<16;h++) ah[h] += p[frr*16+h];
      s1 += p[64+frr];
      s2 += p[68+frr];
    }
    int s = s0 + t;
    size_t base = (size_t)(kh*16 + lb)*16;
    #pragma unroll
    for(int h=0;h<16;h++)
      accP[(base + h)*S_ + s] = ah[h];
    sumP[(size_t)(kh*16+lb)*S_ + s] = s1;
    sqP[(size_t)(kh*16+lb)*S_ + s] = s2;
  }
}

// ---------------- kD2: combine K-halves -> scores, mu, rs ----------------
__global__ __launch_bounds__(256) void kD2(
    const float* __restrict__ accP, const float* __restrict__ sumP, const float* __restrict__ sqP,
    const float* __restrict__ Sg, const float* __restrict__ Sb,
    float* __restrict__ scores, float* __restrict__ mu, float* __restrict__ rs){
  int t = threadIdx.x;
  int b = blockIdx.y, l = blockIdx.z;
  int lb = l*8 + b;
  int s = blockIdx.x*256 + t;
  float s1 = sumP[(size_t)lb*S_ + s] + sumP[(size_t)(16+lb)*S_ + s];
  float s2 = sqP[(size_t)lb*S_ + s]  + sqP[(size_t)(16+lb)*S_ + s];
  float m = s1*(1.0f/D_);
  float var = s2*(1.0f/D_) - m*m;
  float rst = rsqrtf(var + EPS_);
  mu[(size_t)lb*S_ + s] = m;
  rs[(size_t)lb*S_ + s] = rst;
  #pragma unroll
  for (int h=0;h<16;h++){
    float a = accP[((size_t)lb*16 + h)*S_ + s] + accP[((size_t)(16+lb)*16 + h)*S_ + s];
    scores[((size_t)lb*H_ + h)*S_ + s] = rst*(a - m*Sg[lb*H_+h]) + Sb[lb*H_+h];
  }
}

// ---------------- kE1: softmax stats per (l,b,h): M, Sden, c ----------------
__global__ __launch_bounds__(256) void kE1(
    const float* __restrict__ scores, const float* __restrict__ mu, const float* __restrict__ rs,
    float* __restrict__ M, float* __restrict__ Sden, float* __restrict__ cc){
  int t=threadIdx.x; int h=blockIdx.x, b=blockIdx.y, l=blockIdx.z;
  int lb = l*8+b;
  const float* sc = scores + ((size_t)lb*H_ + h)*S_;
  __shared__ float red[256];
  __shared__ float red2[256];
  float mx = -1e30f;
  for (int s=t; s<S_; s+=256) mx = fmaxf(mx, sc[s]);
  red[t]=mx; __syncthreads();
  for(int off=128;off;off>>=1){ if(t<off) red[t]=fmaxf(red[t],red[t+off]); __syncthreads(); }
  float Mv = red[0];
  __syncthreads();
  float se=0.f, sce=0.f;
  const float* mup = mu + (size_t)lb*S_;
  const float* rsp = rs + (size_t)lb*S_;
  for (int s=t; s<S_; s+=256){
    float e = __expf(sc[s]-Mv);
    se += e;
    sce += e*rsp[s]*mup[s];
  }
  red[t]=se; red2[t]=sce; __syncthreads();
  for(int off=128;off;off>>=1){ if(t<off){red[t]+=red[t+off]; red2[t]+=red2[t+off];} __syncthreads(); }
  if(t==0){ M[lb*H_+h]=Mv; Sden[lb*H_+h]=red[0]; cc[lb*H_+h]=red2[0]/red[0]; }
}

// ---------------- kE2: u[l][b][s][h] = softmax * rstd ----------------
__global__ __launch_bounds__(256) void kE2(
    const float* __restrict__ scores, const float* __restrict__ rs,
    const float* __restrict__ M, const float* __restrict__ Sden,
    float* __restrict__ u){
  int t=threadIdx.x; int scb=blockIdx.x, b=blockIdx.y, l=blockIdx.z;
  int lb=l*8+b;
  int lin0 = t*8;
  int sl = lin0 >> 4;
  int h0 = lin0 & 15;
  int s = scb*128 + sl;
  float rstv = rs[(size_t)lb*S_ + s];
  float out[8];
  #pragma unroll
  for(int k=0;k<8;k++){
    int h = h0 + k;
    float e = __expf(scores[((size_t)lb*H_+h)*S_ + s] - M[lb*H_+h]);
    out[k] = e / Sden[lb*H_+h] * rstv;
  }
  float* up = u + ((size_t)lb*S_ + s)*H_ + h0;
  *(float4*)up     = make_float4(out[0],out[1],out[2],out[3]);
  *(float4*)(up+4) = make_float4(out[4],out[5],out[6],out[7]);
}

// ---------------- kF: A partials = sum_s u[h,s]*x[s,d] (reads hs 2nd time) ----------------
__global__ __launch_bounds__(256) void kF(
    const float* __restrict__ hs0, const float* __restrict__ hs1,
    const float* __restrict__ u, float* __restrict__ Fpart){
  int t=threadIdx.x;
  int sc = blockIdx.x>>2, dq = blockIdx.x&3;
  int b=blockIdx.y, l=blockIdx.z;
  int lb=l*8+b;
  const float* hs = (l==0?hs0:hs1) + (size_t)b*S_*D_;
  int d0 = dq*512 + t*2;
  float acc[16][2];
  #pragma unroll
  for(int h=0;h<16;h++){ acc[h][0]=0.f; acc[h][1]=0.f; }
  int s0 = sc*128;
  #pragma unroll 4
  for (int si=0; si<128; si++){
    int s = s0+si;
    const float* up = u + ((size_t)lb*S_ + s)*H_;
    float4 u0 = *(const float4*)up, u1 = *(const float4*)(up+4),
           u2 = *(const float4*)(up+8), u3 = *(const float4*)(up+12);
    float uu[16] = {u0.x,u0.y,u0.z,u0.w, u1.x,u1.y,u1.z,u1.w,
                    u2.x,u2.y,u2.z,u2.w, u3.x,u3.y,u3.z,u3.w};
    float2 x = *(const float2*)(hs + (size_t)s*D_ + d0);
    #pragma unroll
    for(int h=0;h<16;h++){ acc[h][0] += uu[h]*x.x; acc[h][1] += uu[h]*x.y; }
  }
  #pragma unroll
  for(int h=0;h<16;h++)
    *(float2*)(Fpart + (((size_t)lb*16 + sc)*H_ + h)*D_ + d0) = make_float2(acc[h][0], acc[h][1]);
}

// ---------------- kF2: combine partials, mult by gamma -> gAT[l][h][d][b] ----------------
__global__ __launch_bounds__(256) void kF2(
    const float* __restrict__ Fpart, const float* __restrict__ g, float* __restrict__ gAT){
  int n = blockIdx.x*256 + threadIdx.x;   // over l*16*2048 = 65536
  int d = n & (D_-1);
  int h = (n >> 11) & 15;
  int l = n >> 15;
  float gg = g[l*D_+d];
  float out[8];
  #pragma unroll
  for(int b=0;b<8;b++){
    float s=0.f;
    for(int scn=0;scn<16;scn++)
      s += Fpart[(((size_t)(l*8+b)*16 + scn)*H_ + h)*D_ + d];
    out[b]=gg*s;
  }
  float* op = gAT + (size_t)n*8;
  *(float4*)op     = make_float4(out[0],out[1],out[2],out[3]);
  *(float4*)(op+4) = make_float4(out[4],out[5],out[6],out[7]);
}

// ---------------- kG: o partials = gA @ Wv (+ Gv, Bv rows) ----------------
__global__ __launch_bounds__(256) void kG(
    const float* __restrict__ Wv, const float* __restrict__ gAT,
    const float* __restrict__ g, const float* __restrict__ bt,
    float* __restrict__ Opart){
  int t=threadIdx.x;
  int d4=blockIdx.x, h=blockIdx.y, l=blockIdx.z;
  int j = t & 127;
  int dg = rfl(t >> 7);
  const float* wv = Wv + (size_t)l*D_*D_ + h*HD_ + j;
  const float* gA = gAT + ((size_t)l*H_ + h)*D_*8;
  float acc[8]={0,0,0,0,0,0,0,0}; float ag=0.f, ab=0.f;
  int dstart = d4*256 + dg*128;
  #pragma unroll 2
  for (int dd=0; dd<128; dd++){
    int d = dstart+dd;
    float wvv = wv[(size_t)d*D_];
    const float* xa = gA + (size_t)d*8;
    #pragma unroll
    for(int r=0;r<8;r++) acc[r] += xa[r]*wvv;
    ag += g[l*D_+d]*wvv;
    ab += bt[l*D_+d]*wvv;
  }
  __shared__ float red[2][128][10];
  float* p = red[dg][j];
  #pragma unroll
  for(int r=0;r<8;r++) p[r]=acc[r];
  p[8]=ag; p[9]=ab;
  __syncthreads();
  if (t<128){
    const float* q0=red[0][t]; const float* q1=red[1][t];
    #pragma unroll
    for(int r=0;r<10;r++)
      atomicAdd(&Opart[(((size_t)l*H_+h)*HD_ + t)*10 + r], q0[r]+q1[r]);
  }
}

// ---------------- kG2: finalize o -> oT[l][d][b] ----------------
__global__ void kG2(const float* __restrict__ Opart, const float* __restrict__ cc,
                    float* __restrict__ oT){
  int n = blockIdx.x*256 + threadIdx.x;  // over 2*16*128 = 4096
  int j = n & 127; int h = (n>>7) & 15; int l = n>>11;
  const float* p = Opart + (size_t)n*10;
  float ag=p[8], ab=p[9];
  #pragma unroll
  for(int b=0;b<8;b++){
    float c = cc[(l*8+b)*H_+h];
    oT[((size_t)l*D_ + h*HD_ + j)*8 + b] = p[b] - c*ag + ab;
  }
}

// ---------------- kInitH: hcatT = bo broadcast ----------------
__global__ void kInitH(const float* __restrict__ bo, float* __restrict__ hcatT){
  int n = blockIdx.x*256 + threadIdx.x;  // 32768
  hcatT[n] = bo[n>>3];
}

// ---------------- kH2: t1 = gelu(t1 + b1) ----------------
__global__ void kH2(float* __restrict__ t1T, const float* __restrict__ b1){
  int i = blockIdx.x*256 + threadIdx.x;  // 16384
  float bv = b1[i];
  float* p = t1T + (size_t)i*8;
  #pragma unroll
  for(int k=0;k<8;k++){
    float x = p[k] + bv;
    p[k] = 0.5f*x*(1.0f + erff(x*0.70710678118654752440f));
  }
}

// ---------------- kH2b: h2 = hcat + b2 ----------------
__global__ void kH2b(const float* __restrict__ hcatT, const float* __restrict__ b2, float* __restrict__ h2T){
  int j = blockIdx.x*256 + threadIdx.x;  // 4096
  float bv = b2[j];
  #pragma unroll
  for(int k=0;k<8;k++) h2T[(size_t)j*8+k] = hcatT[(size_t)j*8+k] + bv;
}

// ---------------- kH4: logits = h2 @ Wl + bl ----------------
__global__ __launch_bounds__(256) void kH4(const float* __restrict__ h2T, const float* __restrict__ Wl,
                    const float* __restrict__ bl, float* __restrict__ out){
  int t=threadIdx.x;
  float acc[8][2];
  #pragma unroll
  for(int b=0;b<8;b++){acc[b][0]=0.f;acc[b][1]=0.f;}
  for (int j=t; j<DC_; j+=256){
    float w0=Wl[j*2], w1=Wl[j*2+1];
    const float* hp = h2T + (size_t)j*8;
    #pragma unroll
    for(int b=0;b<8;b++){ float x=hp[b]; acc[b][0]+=x*w0; acc[b][1]+=x*w1; }
  }
  __shared__ float red[256][16];
  #pragma unroll
  for(int b=0;b<8;b++){ red[t][b*2]=acc[b][0]; red[t][b*2+1]=acc[b][1]; }
  __syncthreads();
  for(int off=128;off;off>>=1){ if(t<off){ for(int k=0;k<16;k++) red[t][k]+=red[t+off][k]; } __syncthreads(); }
  if (t<16) out[t] = red[0][t] + bl[t&1];
}

extern "C" void kernel_launch(void* const* d_in, const int* in_sizes, int n_in,
                              void* d_out, int out_size, void* d_ws, size_t ws_size,
                              hipStream_t stream) {
  (void)in_sizes; (void)n_in; (void)out_size;
  const float* hs0 = (const float*)d_in[0];
  const float* hs1 = (const float*)d_in[1];
  const int*   ids = (const int*)d_in[2];
  const float* ln_g = (const float*)d_in[3];
  const float* ln_b = (const float*)d_in[4];
  const float* Wq = (const float*)d_in[5];
  const float* Wk = (const float*)d_in[6];
  const float* Wv = (const float*)d_in[7];
  const float* Wo = (const float*)d_in[8];
  const float* bo = (const float*)d_in[9];
  const float* W1 = (const float*)d_in[10];
  const float* b1 = (const float*)d_in[11];
  const float* W2 = (const float*)d_in[12];
  const float* b2 = (const float*)d_in[13];
  const float* Wl = (const float*)d_in[14];
  const float* bl = (const float*)d_in[15];
  float* out = (float*)d_out;
  float* ws = (float*)d_ws;

  size_t o = 0;
  int* idx = (int*)ws;        o += 16;
  // ---- atomic-accumulated region (zero-init) ----
  float* qT = ws + o;         o += (size_t)L_*D_*8;        // 32768
  float* Sg = ws + o;         o += 256;
  float* Sb = ws + o;         o += 256;
  float* Opart = ws + o;      o += (size_t)L_*H_*HD_*10;   // 40960
  float* t1T = ws + o;        o += (size_t)I_*8;           // 131072
  size_t atomicFloats = o - 16;
  // ---- fully-written buffers ----
  float* lnlT = ws + o;       o += (size_t)L_*D_*8;
  float* gqk = ws + o;        o += (size_t)L_*8*H_*D_;
  float* mu = ws + o;         o += (size_t)L_*8*S_;
  float* rs_ = ws + o;        o += (size_t)L_*8*S_;
  float* scores = ws + o;     o += (size_t)L_*8*H_*S_;
  float* M = ws + o;          o += 256;
  float* Sden = ws + o;       o += 256;
  float* cc = ws + o;         o += 256;
  float* u = ws + o;          o += (size_t)L_*8*S_*H_;
  float* Fpart = ws + o;      o += (size_t)L_*8*16*H_*D_;  // 8388608
  float* gAT = ws + o;        o += (size_t)L_*H_*D_*8;
  float* oT = ws + o;         o += (size_t)L_*D_*8;
  float* hcatT = ws + o;      o += (size_t)DC_*8;
  float* h2T = ws + o;        o += (size_t)DC_*8;
  if (o*4 > ws_size) return;  // workspace too small (should not happen)

  // kD partials aliased into Fpart region (dead until kF writes it, after kD2 consumed them)
  float* accP = Fpart;                              // 2*16*16*2048 = 1048576 floats
  float* sumP = Fpart + (size_t)2*16*16*2048;       // 2*16*2048 = 65536
  float* sqP  = sumP + (size_t)2*16*2048;           // 65536   (total 1179648 <= 8388608)

  hipMemsetAsync((void*)(ws + 16), 0, atomicFloats*4, stream);

  kA<<<8,256,0,stream>>>(ids, idx);
  kA2<<<dim3(8,2),256,0,stream>>>(hs0,hs1,idx,ln_g,ln_b,lnlT);
  // q[l,b,:] = lastln @ Wq
  gemv8<<<dim3(32,8,2),256,0,stream>>>(Wq, lnlT, qT, D_, D_, 8,
                                       (long)D_*D_, (long)D_*8, (long)D_*8);
  kC<<<dim3(8,16,2),256,0,stream>>>(Wk, qT, ln_g, ln_b, gqk, Sg, Sb);
  kD<<<dim3(64,8,2),256,0,stream>>>(hs0,hs1,gqk,accP,sumP,sqP);
  kD2<<<dim3(8,8,2),256,0,stream>>>(accP,sumP,sqP,Sg,Sb,scores,mu,rs_);
  kE1<<<dim3(16,8,2),256,0,stream>>>(scores,mu,rs_,M,Sden,cc);
  kE2<<<dim3(16,8,2),256,0,stream>>>(scores,rs_,M,Sden,u);
  kF<<<dim3(64,8,2),256,0,stream>>>(hs0,hs1,u,Fpart);
  kF2<<<256,256,0,stream>>>(Fpart, ln_g, gAT);
  kG<<<dim3(8,16,2),256,0,stream>>>(Wv, gAT, ln_g, ln_b, Opart);
  kG2<<<16,256,0,stream>>>(Opart, cc, oT);
  kInitH<<<128,256,0,stream>>>(bo, hcatT);
  // attn_out = o @ Wo (+bo via init), concat into hcatT
  gemv8<<<dim3(32,8,2),256,0,stream>>>(Wo, oT, hcatT, D_, D_, 8,
                                       (long)D_*D_, (long)D_*8, (long)D_*8);
  // t1 = hcat @ W1
  gemv8<<<dim3(256,4,1),256,0,stream>>>(W1, hcatT, t1T, DC_, I_, 4, 0,0,0);
  kH2<<<64,256,0,stream>>>(t1T, b1);
  kH2b<<<16,256,0,stream>>>(hcatT, b2, h2T);
  // h2 += t1 @ W2
  gemv8<<<dim3(64,16,1),256,0,stream>>>(W2, t1T, h2T, I_, DC_, 16, 0,0,0);
  kH4<<<1,256,0,stream>>>(h2T, Wl, bl, out);
}

// Round 2
// 983.252 us; speedup vs baseline: 1.1533x; 1.0337x over previous
//
#include <hip/hip_runtime.h>
#include <math.h>

#define PAD_ID 50257
#define B_ 8
#define S_ 2048
#define D_ 2048
#define H_ 16
#define HD_ 128
#define L_ 2
#define DC_ 4096
#define I_ 16384
#define EPS_ 1e-5f

__device__ __forceinline__ int rfl(int x){ return __builtin_amdgcn_readfirstlane(x); }

// ---------------- kAB: last non-pad index + LN of last-token row -> lnlT[l][d][b] ----------------
__global__ __launch_bounds__(256) void kAB(const float* __restrict__ hs0, const float* __restrict__ hs1,
                    const int* __restrict__ ids,
                    const float* __restrict__ g, const float* __restrict__ bt,
                    float* __restrict__ lnlT){
  int b = blockIdx.x, l = blockIdx.y, t = threadIdx.x;
  __shared__ int redi[256];
  int best = -1;
  for (int s = t; s < S_; s += 256)
    if (ids[b*S_+s] != PAD_ID) best = s;
  redi[t] = best; __syncthreads();
  for (int off=128; off; off>>=1){ if (t<off) redi[t] = max(redi[t], redi[t+off]); __syncthreads(); }
  int ix = max(redi[0], 0);
  const float* hs = (l==0?hs0:hs1);
  const float* row = hs + ((size_t)b*S_ + ix)*D_;
  int d0 = t*8;
  float x[8]; float s=0.f, ss=0.f;
  #pragma unroll
  for(int k=0;k<8;k++){ x[k]=row[d0+k]; s+=x[k]; ss+=x[k]*x[k]; }
  __shared__ float r1[256], r2[256];
  r1[t]=s; r2[t]=ss; __syncthreads();
  for(int off=128; off; off>>=1){ if(t<off){ r1[t]+=r1[t+off]; r2[t]+=r2[t+off]; } __syncthreads(); }
  float m = r1[0]*(1.0f/D_); float var = r2[0]*(1.0f/D_) - m*m;
  float rstd = rsqrtf(var + EPS_);
  #pragma unroll
  for(int k=0;k<8;k++){
    int d = d0+k;
    lnlT[((size_t)l*D_ + d)*8 + b] = (x[k]-m)*rstd*g[l*D_+d] + bt[l*D_+d];
  }
}

// ---------------- gemv8: outT[i][b] += sum_c Xt[c][b] * W[c][i] (8 rows) ----------------
__global__ __launch_bounds__(256) void gemv8(
    const float* __restrict__ W, const float* __restrict__ Xt, float* __restrict__ outAcc,
    int C, int N, int cs, long wStride, long xStride, long oStride){
  int t = threadIdx.x;
  int l = blockIdx.z;
  W += (size_t)l*wStride; Xt += (size_t)l*xStride; outAcc += (size_t)l*oStride;
  int lane = t & 63;
  int w = rfl(t >> 6);
  int cpw = C/(cs*4);
  int c0 = (blockIdx.y*4 + w)*cpw;
  float acc[8] = {0,0,0,0,0,0,0,0};
  const float* xp = Xt + (size_t)c0*8;
  const float* wp = W + (size_t)c0*N + (size_t)blockIdx.x*64 + lane;
  #pragma unroll 8
  for (int c=0; c<cpw; c++){
    float wv = wp[(size_t)c*N];
    #pragma unroll
    for(int r=0;r<8;r++) acc[r] += xp[c*8+r]*wv;
  }
  __shared__ float red[4][64][8];
  #pragma unroll
  for(int r=0;r<8;r++) red[w][lane][r] = acc[r];
  __syncthreads();
  if (t < 64){
    #pragma unroll
    for(int r=0;r<8;r++){
      float s = red[0][t][r]+red[1][t][r]+red[2][t][r]+red[3][t][r];
      atomicAdd(&outAcc[((size_t)blockIdx.x*64 + t)*8 + r], s);
    }
  }
}

// ---------------- kC: qk -> gqk[l][b][h][d'], Sg, Sb ----------------
__global__ __launch_bounds__(256) void kC(
    const float* __restrict__ Wk, const float* __restrict__ qT,
    const float* __restrict__ g, const float* __restrict__ bt,
    float* __restrict__ gqk, float* __restrict__ Sg, float* __restrict__ Sb){
  int t = threadIdx.x;
  int h = blockIdx.y; int l = blockIdx.z;
  int dp = blockIdx.x*256 + t;
  const float* wr = Wk + (size_t)l*D_*D_ + (size_t)dp*D_ + h*HD_;
  const float* qB = qT + ((size_t)l*D_ + h*HD_)*8;
  float a[8]={0,0,0,0,0,0,0,0};
  #pragma unroll 4
  for (int j4=0;j4<32;j4++){
    float4 wv = *(const float4*)(wr + j4*4);
    const float* qp = qB + j4*32;
    #pragma unroll
    for(int r=0;r<8;r++)
      a[r] += wv.x*qp[r] + wv.y*qp[8+r] + wv.z*qp[16+r] + wv.w*qp[24+r];
  }
  float gg = g[l*D_+dp], bb = bt[l*D_+dp];
  float sgl[8], sbl[8];
  #pragma unroll
  for(int r=0;r<8;r++){
    float gq = gg*a[r];
    gqk[((size_t)(l*8+r)*H_ + h)*D_ + dp] = gq;
    sgl[r] = gq;
    sbl[r] = bb*a[r];
  }
  __shared__ float red[256][8];
  #pragma unroll
  for(int r=0;r<8;r++) red[t][r]=sgl[r];
  __syncthreads();
  for(int off=128; off; off>>=1){ if(t<off){ for(int r=0;r<8;r++) red[t][r]+=red[t+off][r]; } __syncthreads(); }
  if (t<8) atomicAdd(&Sg[(l*8+t)*H_ + h], red[0][t]);
  __syncthreads();
  #pragma unroll
  for(int r=0;r<8;r++) red[t][r]=sbl[r];
  __syncthreads();
  for(int off=128; off; off>>=1){ if(t<off){ for(int r=0;r<8;r++) red[t][r]+=red[t+off][r]; } __syncthreads(); }
  if (t<8) atomicAdd(&Sb[(l*8+t)*H_ + h], red[0][t]);
}

// ---------------- kD: scores partials (K-split x4, R=4 rows, XOR-swizzled x tile) ----------------
// accP[kh][lb][h][s], sumP[kh][lb][s], sqP[kh][lb][s]
__global__ __launch_bounds__(256) void kD(
    const float* __restrict__ hs0, const float* __restrict__ hs1,
    const float* __restrict__ gqk,
    float* __restrict__ accP, float* __restrict__ sumP, float* __restrict__ sqP){
  int t = threadIdx.x;
  int sc = blockIdx.x & 31, kh = blockIdx.x >> 5;   // kh in [0,4)
  int b = blockIdx.y, l = blockIdx.z;
  int lb = l*8 + b;
  const float* hs = (l==0?hs0:hs1) + (size_t)b*S_*D_;
  const float* gqp = gqk + (size_t)lb*H_*D_;
  int s0 = sc*64;
  int kb = kh*512;
  __shared__ float smem[64*64 + 16*68];   // x tile [64][64] XOR-swz + gq tile [16][68]; reused as redL[64][73]
  float* xT = smem;
  float* gT = smem + 64*64;
  int rq = t & 15, jg = t >> 4;     // row quad (4 rows), col group (4 cols)
  int r0 = rq*4;
  float acc[4][16];
  #pragma unroll
  for(int rr=0;rr<4;rr++){
    #pragma unroll
    for(int h=0;h<16;h++) acc[rr][h]=0.f;
  }
  float sum[4]={0.f,0.f,0.f,0.f}, sq[4]={0.f,0.f,0.f,0.f};
  for (int c=0;c<8;c++){
    int cb = kb + c*64;
    // stage X tile [64 rows][64 cols], col4-group XOR-swizzled by row&7
    #pragma unroll
    for (int q=0;q<4;q++){
      int fid = t + q*256;
      int row = fid >> 4, jo4 = fid & 15;
      float4 v = *(const float4*)(hs + (size_t)(s0+row)*D_ + cb + jo4*4);
      *(float4*)&xT[(row<<6) + ((jo4 ^ (row&7))<<2)] = v;
    }
    // stage gq tile [16 h][64 cols]
    {
      int hh = t >> 4, jo = (t & 15)*4;
      float4 gv = *(const float4*)(gqp + (size_t)hh*D_ + cb + jo);
      *(float4*)&gT[hh*68 + jo] = gv;
    }
    __syncthreads();
    float xv[4][4];
    #pragma unroll
    for (int rr=0;rr<4;rr++){
      int row = r0+rr;
      float4 x4 = *(const float4*)&xT[(row<<6) + ((jg ^ (row&7))<<2)];
      xv[rr][0]=x4.x; xv[rr][1]=x4.y; xv[rr][2]=x4.z; xv[rr][3]=x4.w;
      sum[rr] += x4.x + x4.y + x4.z + x4.w;
      sq[rr]  += x4.x*x4.x + x4.y*x4.y + x4.z*x4.z + x4.w*x4.w;
    }
    #pragma unroll
    for (int h=0;h<16;h++){
      float4 gv = *(const float4*)&gT[h*68 + jg*4];
      #pragma unroll
      for (int rr=0;rr<4;rr++)
        acc[rr][h] += xv[rr][0]*gv.x + xv[rr][1]*gv.y + xv[rr][2]*gv.z + xv[rr][3]*gv.w;
    }
    __syncthreads();
  }
  // reduce over the 4 col-groups inside each wave (lane bits 4,5)
  #pragma unroll
  for (int rr=0;rr<4;rr++){
    #pragma unroll
    for (int h=0;h<16;h++){
      float v = acc[rr][h];
      v += __shfl_xor(v, 16);
      v += __shfl_xor(v, 32);
      acc[rr][h] = v;
    }
    float sv = sum[rr]; sv += __shfl_xor(sv, 16); sv += __shfl_xor(sv, 32); sum[rr] = sv;
    float qv = sq[rr];  qv += __shfl_xor(qv, 16); qv += __shfl_xor(qv, 32); sq[rr]  = qv;
  }
  __syncthreads();   // done with xT/gT, reuse as redL
  float* redL = smem;  // [64 entries][73]
  int w = t >> 6;
  if ((t & 63) < 16){
    float* p = &redL[(w*16 + rq)*73];
    #pragma unroll
    for (int rr=0;rr<4;rr++){
      #pragma unroll
      for (int h=0;h<16;h++) p[rr*16+h] = acc[rr][h];
      p[64+rr] = sum[rr];
      p[68+rr] = sq[rr];
    }
  }
  __syncthreads();
  if (t < 64){
    int frq = t >> 2, frr = t & 3;
    float ah[16];
    #pragma unroll
    for(int h=0;h<16;h++) ah[h]=0.f;
    float s1=0.f, s2=0.f;
    #pragma unroll
    for (int ww=0; ww<4; ww++){
      const float* p = &redL[(ww*16 + frq)*73];
      #pragma unroll
      for(int h=0;h<16;h++) ah[h] += p[frr*16+h];
      s1 += p[64+frr];
      s2 += p[68+frr];
    }
    int s = s0 + t;
    size_t base = (size_t)(kh*16 + lb)*16;
    #pragma unroll
    for(int h=0;h<16;h++)
      accP[(base + h)*S_ + s] = ah[h];
    sumP[(size_t)(kh*16+lb)*S_ + s] = s1;
    sqP[(size_t)(kh*16+lb)*S_ + s] = s2;
  }
}

// ---------------- kD2: combine K-quarters -> scores, mu, rs + per-block max PM ----------------
__global__ __launch_bounds__(256) void kD2(
    const float* __restrict__ accP, const float* __restrict__ sumP, const float* __restrict__ sqP,
    const float* __restrict__ Sg, const float* __restrict__ Sb,
    float* __restrict__ scores, float* __restrict__ mu, float* __restrict__ rs,
    float* __restrict__ PM){
  int t = threadIdx.x;
  int b = blockIdx.y, l = blockIdx.z;
  int lb = l*8 + b;
  int s = blockIdx.x*256 + t;
  float s1 = 0.f, s2 = 0.f;
  #pragma unroll
  for (int kh=0; kh<4; kh++){
    s1 += sumP[(size_t)(kh*16+lb)*S_ + s];
    s2 += sqP[(size_t)(kh*16+lb)*S_ + s];
  }
  float m = s1*(1.0f/D_);
  float var = s2*(1.0f/D_) - m*m;
  float rst = rsqrtf(var + EPS_);
  mu[(size_t)lb*S_ + s] = m;
  rs[(size_t)lb*S_ + s] = rst;
  __shared__ float redm[256][17];
  #pragma unroll
  for (int h=0;h<16;h++){
    float a = 0.f;
    #pragma unroll
    for (int kh=0; kh<4; kh++)
      a += accP[((size_t)(kh*16+lb)*16 + h)*S_ + s];
    float scv = rst*(a - m*Sg[lb*H_+h]) + Sb[lb*H_+h];
    scores[((size_t)lb*H_ + h)*S_ + s] = scv;
    redm[t][h] = scv;
  }
  __syncthreads();
  for(int off=128;off;off>>=1){
    if(t<off){
      #pragma unroll
      for(int h=0;h<16;h++) redm[t][h] = fmaxf(redm[t][h], redm[t+off][h]);
    }
    __syncthreads();
  }
  if (t<16) PM[(lb*H_ + t)*8 + blockIdx.x] = redm[0][t];
}

// ---------------- kE2: u_un[l][b][s][h] = exp(sc-M)*rstd; atomic Sden/Sce partials ----------------
__global__ __launch_bounds__(256) void kE2(
    const float* __restrict__ scores, const float* __restrict__ rs, const float* __restrict__ mu,
    const float* __restrict__ PM,
    float* __restrict__ u, float* __restrict__ SdenP, float* __restrict__ SceP){
  int t=threadIdx.x; int scb=blockIdx.x, b=blockIdx.y, l=blockIdx.z;
  int lb=l*8+b;
  __shared__ float Mh[16];
  if (t < 16){
    float m = -1e30f;
    #pragma unroll
    for (int sb=0; sb<8; sb++) m = fmaxf(m, PM[(lb*H_ + t)*8 + sb]);
    Mh[t] = m;
  }
  __syncthreads();
  int sl = t >> 1;
  int h0 = (t & 1)*8;
  int s = scb*128 + sl;
  float rstv = rs[(size_t)lb*S_ + s];
  float muv  = mu[(size_t)lb*S_ + s];
  float out[8];
  __shared__ float se[256][9], sce[256][9];
  #pragma unroll
  for(int k=0;k<8;k++){
    int h = h0 + k;
    float e = __expf(scores[((size_t)lb*H_+h)*S_ + s] - Mh[h]);
    out[k] = e * rstv;
    se[t][k] = e;
    sce[t][k] = e * rstv * muv;
  }
  float* up = u + ((size_t)lb*S_ + s)*H_ + h0;
  *(float4*)up     = make_float4(out[0],out[1],out[2],out[3]);
  *(float4*)(up+4) = make_float4(out[4],out[5],out[6],out[7]);
  __syncthreads();
  for(int off=128; off>=2; off>>=1){
    if(t<off){
      #pragma unroll
      for(int k=0;k<8;k++){ se[t][k]+=se[t+off][k]; sce[t][k]+=sce[t+off][k]; }
    }
    __syncthreads();
  }
  if (t==0){
    #pragma unroll
    for(int k=0;k<8;k++){
      atomicAdd(&SdenP[lb*H_ + k], se[0][k]);
      atomicAdd(&SceP[lb*H_ + k], sce[0][k]);
    }
  }
  if (t==1){
    #pragma unroll
    for(int k=0;k<8;k++){
      atomicAdd(&SdenP[lb*H_ + 8 + k], se[1][k]);
      atomicAdd(&SceP[lb*H_ + 8 + k], sce[1][k]);
    }
  }
}

// ---------------- kF: A partials = sum_s u_un[h,s]*x[s,d] (reads hs 2nd time) ----------------
__global__ __launch_bounds__(256) void kF(
    const float* __restrict__ hs0, const float* __restrict__ hs1,
    const float* __restrict__ u, float* __restrict__ Fpart){
  int t=threadIdx.x;
  int sc = blockIdx.x>>2, dq = blockIdx.x&3;
  int b=blockIdx.y, l=blockIdx.z;
  int lb=l*8+b;
  const float* hs = (l==0?hs0:hs1) + (size_t)b*S_*D_;
  int d0 = dq*512 + t*2;
  float acc[16][2];
  #pragma unroll
  for(int h=0;h<16;h++){ acc[h][0]=0.f; acc[h][1]=0.f; }
  int s0 = sc*128;
  #pragma unroll 4
  for (int si=0; si<128; si++){
    int s = s0+si;
    const float* up = u + ((size_t)lb*S_ + s)*H_;
    float4 u0 = *(const float4*)up, u1 = *(const float4*)(up+4),
           u2 = *(const float4*)(up+8), u3 = *(const float4*)(up+12);
    float uu[16] = {u0.x,u0.y,u0.z,u0.w, u1.x,u1.y,u1.z,u1.w,
                    u2.x,u2.y,u2.z,u2.w, u3.x,u3.y,u3.z,u3.w};
    float2 x = *(const float2*)(hs + (size_t)s*D_ + d0);
    #pragma unroll
    for(int h=0;h<16;h++){ acc[h][0] += uu[h]*x.x; acc[h][1] += uu[h]*x.y; }
  }
  #pragma unroll
  for(int h=0;h<16;h++)
    *(float2*)(Fpart + (((size_t)lb*16 + sc)*H_ + h)*D_ + d0) = make_float2(acc[h][0], acc[h][1]);
}

// ---------------- kF2: combine partials, * gamma / Sden -> gAT[l][h][d][b] ----------------
__global__ __launch_bounds__(256) void kF2(
    const float* __restrict__ Fpart, const float* __restrict__ g,
    const float* __restrict__ SdenP, float* __restrict__ gAT){
  int n = blockIdx.x*256 + threadIdx.x;   // over l*16*2048 = 65536
  int d = n & (D_-1);
  int h = (n >> 11) & 15;
  int l = n >> 15;
  float gg = g[l*D_+d];
  float out[8];
  #pragma unroll
  for(int b=0;b<8;b++){
    float s=0.f;
    for(int scn=0;scn<16;scn++)
      s += Fpart[(((size_t)(l*8+b)*16 + scn)*H_ + h)*D_ + d];
    out[b] = gg*s/SdenP[(l*8+b)*H_ + h];
  }
  float* op = gAT + (size_t)n*8;
  *(float4*)op     = make_float4(out[0],out[1],out[2],out[3]);
  *(float4*)(op+4) = make_float4(out[4],out[5],out[6],out[7]);
}

// ---------------- kG: o partials = gA @ Wv (+ Gv, Bv rows) ----------------
__global__ __launch_bounds__(256) void kG(
    const float* __restrict__ Wv, const float* __restrict__ gAT,
    const float* __restrict__ g, const float* __restrict__ bt,
    float* __restrict__ Opart){
  int t=threadIdx.x;
  int d4=blockIdx.x, h=blockIdx.y, l=blockIdx.z;
  int j = t & 127;
  int dg = rfl(t >> 7);
  const float* wv = Wv + (size_t)l*D_*D_ + h*HD_ + j;
  const float* gA = gAT + ((size_t)l*H_ + h)*D_*8;
  float acc[8]={0,0,0,0,0,0,0,0}; float ag=0.f, ab=0.f;
  int dstart = d4*256 + dg*128;
  #pragma unroll 2
  for (int dd=0; dd<128; dd++){
    int d = dstart+dd;
    float wvv = wv[(size_t)d*D_];
    const float* xa = gA + (size_t)d*8;
    #pragma unroll
    for(int r=0;r<8;r++) acc[r] += xa[r]*wvv;
    ag += g[l*D_+d]*wvv;
    ab += bt[l*D_+d]*wvv;
  }
  __shared__ float red[2][128][10];
  float* p = red[dg][j];
  #pragma unroll
  for(int r=0;r<8;r++) p[r]=acc[r];
  p[8]=ag; p[9]=ab;
  __syncthreads();
  if (t<128){
    const float* q0=red[0][t]; const float* q1=red[1][t];
    #pragma unroll
    for(int r=0;r<10;r++)
      atomicAdd(&Opart[(((size_t)l*H_+h)*HD_ + t)*10 + r], q0[r]+q1[r]);
  }
}

// ---------------- kG2i: finalize o -> oT[l][d][b]  AND  hcatT = bo broadcast ----------------
__global__ __launch_bounds__(256) void kG2i(const float* __restrict__ Opart,
                    const float* __restrict__ SdenP, const float* __restrict__ SceP,
                    const float* __restrict__ bo,
                    float* __restrict__ oT, float* __restrict__ hcatT){
  int n = blockIdx.x*256 + threadIdx.x;  // 4096 kG2 items + 32768 init items
  if (n < 4096){
    int j = n & 127; int h = (n>>7) & 15; int l = n>>11;
    const float* p = Opart + (size_t)n*10;
    float ag=p[8], ab=p[9];
    #pragma unroll
    for(int b=0;b<8;b++){
      int lb = l*8+b;
      float c = SceP[lb*H_+h] / SdenP[lb*H_+h];
      oT[((size_t)l*D_ + h*HD_ + j)*8 + b] = p[b] - c*ag + ab;
    }
  } else {
    int m = n - 4096;           // 32768
    hcatT[m] = bo[m>>3];
  }
}

// ---------------- kH2f: t1 = gelu(t1 + b1)  AND  h2 = hcat + b2 ----------------
__global__ __launch_bounds__(256) void kH2f(float* __restrict__ t1T, const float* __restrict__ b1,
                    const float* __restrict__ hcatT, const float* __restrict__ b2,
                    float* __restrict__ h2T){
  int bx = blockIdx.x, t = threadIdx.x;
  if (bx < 64){
    int i = bx*256 + t;  // 16384
    float bv = b1[i];
    float* p = t1T + (size_t)i*8;
    #pragma unroll
    for(int k=0;k<8;k++){
      float x = p[k] + bv;
      p[k] = 0.5f*x*(1.0f + erff(x*0.70710678118654752440f));
    }
  } else {
    int j = (bx-64)*256 + t;  // 4096
    float bv = b2[j];
    #pragma unroll
    for(int k=0;k<8;k++) h2T[(size_t)j*8+k] = hcatT[(size_t)j*8+k] + bv;
  }
}

// ---------------- kH4: logits = h2 @ Wl + bl (8 blocks, atomic) ----------------
__global__ __launch_bounds__(256) void kH4(const float* __restrict__ h2T, const float* __restrict__ Wl,
                    const float* __restrict__ bl, float* __restrict__ out){
  int t=threadIdx.x, bx=blockIdx.x;
  float acc[8][2];
  #pragma unroll
  for(int b=0;b<8;b++){acc[b][0]=0.f;acc[b][1]=0.f;}
  int j0 = bx*512;
  #pragma unroll
  for (int jj=0; jj<2; jj++){
    int j = j0 + jj*256 + t;
    float w0=Wl[j*2], w1=Wl[j*2+1];
    const float* hp = h2T + (size_t)j*8;
    #pragma unroll
    for(int b=0;b<8;b++){ float x=hp[b]; acc[b][0]+=x*w0; acc[b][1]+=x*w1; }
  }
  __shared__ float red[256][16];
  #pragma unroll
  for(int b=0;b<8;b++){ red[t][b*2]=acc[b][0]; red[t][b*2+1]=acc[b][1]; }
  __syncthreads();
  for(int off=128;off;off>>=1){ if(t<off){ for(int k=0;k<16;k++) red[t][k]+=red[t+off][k]; } __syncthreads(); }
  if (t<16) atomicAdd(&out[t], red[0][t] + (bx==0 ? bl[t&1] : 0.f));
}

extern "C" void kernel_launch(void* const* d_in, const int* in_sizes, int n_in,
                              void* d_out, int out_size, void* d_ws, size_t ws_size,
                              hipStream_t stream) {
  (void)in_sizes; (void)n_in; (void)out_size;
  const float* hs0 = (const float*)d_in[0];
  const float* hs1 = (const float*)d_in[1];
  const int*   ids = (const int*)d_in[2];
  const float* ln_g = (const float*)d_in[3];
  const float* ln_b = (const float*)d_in[4];
  const float* Wq = (const float*)d_in[5];
  const float* Wk = (const float*)d_in[6];
  const float* Wv = (const float*)d_in[7];
  const float* Wo = (const float*)d_in[8];
  const float* bo = (const float*)d_in[9];
  const float* W1 = (const float*)d_in[10];
  const float* b1 = (const float*)d_in[11];
  const float* W2 = (const float*)d_in[12];
  const float* b2 = (const float*)d_in[13];
  const float* Wl = (const float*)d_in[14];
  const float* bl = (const float*)d_in[15];
  float* out = (float*)d_out;
  float* ws = (float*)d_ws;

  size_t o = 0;
  o += 16;  // (pad; idx no longer needed)
  // ---- atomic-accumulated region (zero-init) ----
  float* qT = ws + o;         o += (size_t)L_*D_*8;        // 32768
  float* Sg = ws + o;         o += 256;
  float* Sb = ws + o;         o += 256;
  float* Opart = ws + o;      o += (size_t)L_*H_*HD_*10;   // 40960
  float* t1T = ws + o;        o += (size_t)I_*8;           // 131072
  float* SdenP = ws + o;      o += 256;
  float* SceP = ws + o;       o += 256;
  size_t atomicFloats = o - 16;
  // ---- fully-written buffers ----
  float* lnlT = ws + o;       o += (size_t)L_*D_*8;
  float* gqk = ws + o;        o += (size_t)L_*8*H_*D_;
  float* mu = ws + o;         o += (size_t)L_*8*S_;
  float* rs_ = ws + o;        o += (size_t)L_*8*S_;
  float* scores = ws + o;     o += (size_t)L_*8*H_*S_;
  float* PM = ws + o;         o += 2048;                   // [lb][h][8]
  float* u = ws + o;          o += (size_t)L_*8*S_*H_;
  float* Fpart = ws + o;      o += (size_t)L_*8*16*H_*D_;  // 8388608
  float* gAT = ws + o;        o += (size_t)L_*H_*D_*8;
  float* oT = ws + o;         o += (size_t)L_*D_*8;
  float* hcatT = ws + o;      o += (size_t)DC_*8;
  float* h2T = ws + o;        o += (size_t)DC_*8;
  if (o*4 > ws_size) return;  // workspace too small (should not happen)

  // kD partials aliased into Fpart region (dead until kF writes it, after kD2 consumed them)
  float* accP = Fpart;                              // 4*16*16*2048 = 2097152 floats
  float* sumP = Fpart + (size_t)4*16*16*2048;       // 4*16*2048 = 131072
  float* sqP  = sumP + (size_t)4*16*2048;           // 131072   (total 2359296 <= 8388608)

  hipMemsetAsync((void*)(ws + 16), 0, atomicFloats*4, stream);
  hipMemsetAsync((void*)out, 0, 16*4, stream);

  kAB<<<dim3(8,2),256,0,stream>>>(hs0,hs1,ids,ln_g,ln_b,lnlT);
  // q[l,b,:] = lastln @ Wq
  gemv8<<<dim3(32,8,2),256,0,stream>>>(Wq, lnlT, qT, D_, D_, 8,
                                       (long)D_*D_, (long)D_*8, (long)D_*8);
  kC<<<dim3(8,16,2),256,0,stream>>>(Wk, qT, ln_g, ln_b, gqk, Sg, Sb);
  kD<<<dim3(128,8,2),256,0,stream>>>(hs0,hs1,gqk,accP,sumP,sqP);
  kD2<<<dim3(8,8,2),256,0,stream>>>(accP,sumP,sqP,Sg,Sb,scores,mu,rs_,PM);
  kE2<<<dim3(16,8,2),256,0,stream>>>(scores,rs_,mu,PM,u,SdenP,SceP);
  kF<<<dim3(64,8,2),256,0,stream>>>(hs0,hs1,u,Fpart);
  kF2<<<256,256,0,stream>>>(Fpart, ln_g, SdenP, gAT);
  kG<<<dim3(8,16,2),256,0,stream>>>(Wv, gAT, ln_g, ln_b, Opart);
  kG2i<<<144,256,0,stream>>>(Opart, SdenP, SceP, bo, oT, hcatT);
  // attn_out = o @ Wo (+bo via init), concat into hcatT
  gemv8<<<dim3(32,8,2),256,0,stream>>>(Wo, oT, hcatT, D_, D_, 8,
                                       (long)D_*D_, (long)D_*8, (long)D_*8);
  // t1 = hcat @ W1
  gemv8<<<dim3(256,8,1),256,0,stream>>>(W1, hcatT, t1T, DC_, I_, 8, 0,0,0);
  kH2f<<<80,256,0,stream>>>(t1T, b1, hcatT, b2, h2T);
  // h2 += t1 @ W2
  gemv8<<<dim3(64,32,1),256,0,stream>>>(W2, t1T, h2T, I_, DC_, 32, 0,0,0);
  kH4<<<8,256,0,stream>>>(h2T, Wl, bl, out);
}